// Round 5
// baseline (220.753 us; speedup 1.0000x reference)
//
#include <hip/hip_runtime.h>
#include <hip/hip_bf16.h>
#include <stdint.h>

// B=32, S=4096, ENC=512, DEC=512
// out = softmax_s( sum_d tanh( enc @ W_e^T + dh @ W_h^T + b ) * v )

typedef __attribute__((ext_vector_type(8))) short short8;
typedef __attribute__((ext_vector_type(4))) float f32x4;

static __device__ __forceinline__ short8 cvt8(float4 a, float4 b) {
    // 4x v_cvt_pk_bf16_f32 (RNE) via compiler intrinsics
    union { short8 s; __hip_bfloat162 h[4]; } u;
    u.h[0] = __float22bfloat162_rn(float2{a.x, a.y});
    u.h[1] = __float22bfloat162_rn(float2{a.z, a.w});
    u.h[2] = __float22bfloat162_rn(float2{b.x, b.y});
    u.h[3] = __float22bfloat162_rn(float2{b.z, b.w});
    return u.s;
}

static __device__ __forceinline__ float tanh_fast(float x) {
    // tanh(x) = 1 - 2/(exp(2x)+1); overflow->+1, underflow->-1 (both correct)
    return 1.0f - 2.0f / (__expf(2.0f * x) + 1.0f);
}

// ---------------------------------------------------------------------------
// Kernel 1 (96 blocks x 512):
//   blocks 0..63 : W_e (= W_attn[:,512:]) -> bf16, LINEAR [n(512)][k(512)]
//                  (1 KB rows) -- read directly as MFMA B-fragments later.
//   blocks 64..95: proj1[b][e] = sum_d dh[b,d]*W_attn[e,d] + b_attn[e]
// ---------------------------------------------------------------------------
__global__ __launch_bounds__(512) void prep_kernel(
    const float* __restrict__ dh, const float* __restrict__ W_attn,
    const float* __restrict__ b_attn, unsigned short* __restrict__ wsB,
    float* __restrict__ wsP1) {
    __shared__ float dhs[512];
    const int tid = threadIdx.x;
    if (blockIdx.x < 64) {
        int idx = blockIdx.x * 512 + tid;       // 0..32767
        int n  = idx >> 6;                      // W_e row (output dim d)
        int c8 = idx & 63;                      // 8-elem chunk in row
        const float* src = W_attn + (size_t)n * 1024 + 512 + c8 * 8;
        float4 f0 = *(const float4*)(src);
        float4 f1 = *(const float4*)(src + 4);
        *(short8*)((char*)wsB + (size_t)n * 1024 + c8 * 16) = cvt8(f0, f1);
    } else {
        int b = blockIdx.x - 64;
        dhs[tid] = dh[b * 512 + tid];
        __syncthreads();
        const float* wrow = W_attn + (size_t)tid * 1024;  // W_h row e=tid
        float acc = 0.f;
        #pragma unroll 8
        for (int d = 0; d < 512; d += 4) {
            float4 w = *(const float4*)(wrow + d);
            acc += dhs[d] * w.x + dhs[d + 1] * w.y + dhs[d + 2] * w.z + dhs[d + 3] * w.w;
        }
        wsP1[b * 512 + tid] = acc + b_attn[tid];
    }
}

// ---------------------------------------------------------------------------
// Kernel 2: fused GEMM (64 rows x 256 cols per block, K=512) + tanh + v-dot.
// 256 thr = 4 waves, 1M x 4N; wave tile 64x64 = 4x4 frags of 16x16x32 bf16.
// A: f32 -> bf16 staged in 2x8KB LDS (double-buffered, ONE barrier per kt).
// B: loaded DIRECTLY from L2-resident wsB into MFMA registers -- no LDS, no
// barrier coupling. 16 KB LDS + ~150 VGPR -> 3 blocks/CU (12 waves), compiler
// free to pipeline B loads under MFMAs.
// cb=0 writes partial scores to out, cb=1 to wsS1; softmax adds them.
// ---------------------------------------------------------------------------
__global__ __launch_bounds__(256, 3) void fused_kernel(
    const float* __restrict__ enc, const unsigned short* __restrict__ wsB,
    const float* __restrict__ wsP1, const float* __restrict__ vvec,
    float* __restrict__ out, float* __restrict__ wsS1) {
    __shared__ char lds[16384];
    char* const Ab[2] = { lds, lds + 8192 };     // [64][128B] bf16, swizzled

    const int tid  = threadIdx.x;
    const int wc   = tid >> 6;                    // wave = N-block 0..3
    const int lane = tid & 63;
    const int llo  = lane & 15, lhi = lane >> 4;

    // XCD-chunked bijective swizzle (4096 % 8 == 0). (rb, cb=0/1) pairs are
    // adjacent logical blocks -> same XCD -> enc A-tile L2-hot across pair.
    const int bid = blockIdx.x;
    const int lb  = (bid & 7) * 512 + (bid >> 3);
    const int rb  = lb >> 1, cb = lb & 1;
    const int m0  = rb * 64;
    const int b   = m0 >> 12;                     // batch (64 | 4096)

    // A staging map: thread -> (row ar, 16-f32 K chunk ac)
    const int ar = tid >> 2, ac = tid & 3;
    const float* aptr = enc + (size_t)(m0 + ar) * 512 + ac * 16;
    const int aoff0 = ar * 128 + (((ac * 32)     ) ^ ((ar & 7) << 4));
    const int aoff1 = ar * 128 + (((ac * 32) + 16) ^ ((ar & 7) << 4));

    // B fragment base: lane (llo,lhi) of frag (ni,kk) reads
    // wsB[n = cb*256 + wc*64 + ni*16 + llo][k = kt*64 + kk*32 + lhi*8]
    const char* blane = (const char*)wsB +
                        (size_t)(cb * 256 + wc * 64 + llo) * 1024 + lhi * 16;

    f32x4 acc[4][4] = {};
    float4 fa0, fa1, fa2, fa3;

    #define A_LOAD(kt)                                 \
        do { const float* p_ = aptr + (kt) * 64;       \
             fa0 = *(const float4*)(p_);               \
             fa1 = *(const float4*)(p_ + 4);           \
             fa2 = *(const float4*)(p_ + 8);           \
             fa3 = *(const float4*)(p_ + 12); } while (0)

    #define A_WRITE(Adst)                              \
        do { *(short8*)((Adst) + aoff0) = cvt8(fa0, fa1); \
             *(short8*)((Adst) + aoff1) = cvt8(fa2, fa3); } while (0)

    #define COMPUTE(Asrc, kt)                                                      \
        do { const char* bk_ = blane + (kt) * 128;                                 \
             short8 bfr[8];                                                        \
             _Pragma("unroll")                                                     \
             for (int ni = 0; ni < 4; ++ni) {                                      \
                 bfr[ni * 2]     = *(const short8*)(bk_ + ni * 16384);             \
                 bfr[ni * 2 + 1] = *(const short8*)(bk_ + ni * 16384 + 64);        \
             }                                                                     \
             _Pragma("unroll")                                                     \
             for (int kk = 0; kk < 2; ++kk) {                                      \
                 const int gbyte = kk * 64 + lhi * 16;                             \
                 short8 af[4];                                                     \
                 _Pragma("unroll")                                                 \
                 for (int mi = 0; mi < 4; ++mi) {                                  \
                     int row = mi * 16 + llo;                                      \
                     af[mi] = *(const short8*)((Asrc) + row * 128 +                \
                                               (gbyte ^ ((row & 7) << 4)));        \
                 }                                                                 \
                 _Pragma("unroll")                                                 \
                 for (int mi = 0; mi < 4; ++mi)                                    \
                     _Pragma("unroll")                                             \
                     for (int ni = 0; ni < 4; ++ni)                                \
                         acc[mi][ni] = __builtin_amdgcn_mfma_f32_16x16x32_bf16(    \
                             af[mi], bfr[ni * 2 + kk], acc[mi][ni], 0, 0, 0);      \
             } } while (0)

    // prologue: stage A tile 0
    A_LOAD(0);
    A_WRITE(Ab[0]);
    __syncthreads();

    #pragma unroll
    for (int kt = 0; kt < 8; ++kt) {
        if (kt < 7) A_LOAD(kt + 1);     // HBM loads in flight under compute
        COMPUTE(Ab[kt & 1], kt);        // B direct from L2, A frags from LDS
        if (kt < 7) A_WRITE(Ab[(kt + 1) & 1]);
        __syncthreads();                // publish A(kt+1); only 8KB coupled
    }

    // --- epilogue: tanh(acc + proj1[b,d]) * v[d], partial-reduce over d ---
    float p1v[4], vv[4];
    #pragma unroll
    for (int ni = 0; ni < 4; ++ni) {
        int d = cb * 256 + wc * 64 + ni * 16 + llo;
        p1v[ni] = wsP1[b * 512 + d];
        vv[ni]  = vvec[d];
    }
    float part[16];
    #pragma unroll
    for (int mi = 0; mi < 4; ++mi)
        #pragma unroll
        for (int r = 0; r < 4; ++r) {
            float s = 0.f;
            #pragma unroll
            for (int ni = 0; ni < 4; ++ni)
                s += tanh_fast(acc[mi][ni][r] + p1v[ni]) * vv[ni];
            part[mi * 4 + r] = s;
        }
    // reduce across the 16-lane column group (lane bits 0..3)
    #pragma unroll
    for (int off = 1; off < 16; off <<= 1)
        #pragma unroll
        for (int i = 0; i < 16; ++i)
            part[i] += __shfl_xor(part[i], off, 64);

    float* red = (float*)lds;   // [4 wc][64 rows]; K-loop done, safe to reuse
    if (llo == 0) {
        #pragma unroll
        for (int mi = 0; mi < 4; ++mi)
            #pragma unroll
            for (int r = 0; r < 4; ++r)
                red[wc * 64 + mi * 16 + lhi * 4 + r] = part[mi * 4 + r];
    }
    __syncthreads();
    if (tid < 64) {
        float s = red[tid] + red[64 + tid] + red[128 + tid] + red[192 + tid];
        (cb ? wsS1 : out)[m0 + tid] = s;
    }
}

// ---------------------------------------------------------------------------
// Kernel 3: add the two column-half partials, row softmax over S=4096,
// write to out. 32 blocks x 256.
// ---------------------------------------------------------------------------
__global__ __launch_bounds__(256) void softmax_kernel(
    float* __restrict__ out, const float* __restrict__ wsS1) {
    __shared__ float wred[8];
    const int b = blockIdx.x, tid = threadIdx.x;
    float* row = out + (size_t)b * 4096;
    const float* row1 = wsS1 + (size_t)b * 4096;
    float vals[16];
    float lmax = -1e30f;
    #pragma unroll
    for (int i = 0; i < 16; ++i) {
        vals[i] = row[i * 256 + tid] + row1[i * 256 + tid];
        lmax = fmaxf(lmax, vals[i]);
    }
    #pragma unroll
    for (int off = 32; off >= 1; off >>= 1)
        lmax = fmaxf(lmax, __shfl_xor(lmax, off, 64));
    if ((tid & 63) == 0) wred[tid >> 6] = lmax;
    __syncthreads();
    float gmax = fmaxf(fmaxf(wred[0], wred[1]), fmaxf(wred[2], wred[3]));
    float lsum = 0.f;
    #pragma unroll
    for (int i = 0; i < 16; ++i) {
        vals[i] = expf(vals[i] - gmax);
        lsum += vals[i];
    }
    #pragma unroll
    for (int off = 32; off >= 1; off >>= 1)
        lsum += __shfl_xor(lsum, off, 64);
    if ((tid & 63) == 0) wred[4 + (tid >> 6)] = lsum;
    __syncthreads();
    float inv = 1.f / (wred[4] + wred[5] + wred[6] + wred[7]);
    #pragma unroll
    for (int i = 0; i < 16; ++i)
        row[i * 256 + tid] = vals[i] * inv;
}

extern "C" void kernel_launch(void* const* d_in, const int* in_sizes, int n_in,
                              void* d_out, int out_size, void* d_ws, size_t ws_size,
                              hipStream_t stream) {
    const float* dh   = (const float*)d_in[0];   // (32, 512)
    const float* enc  = (const float*)d_in[1];   // (32, 4096, 512)
    const float* Wat  = (const float*)d_in[2];   // (512, 1024)
    const float* batt = (const float*)d_in[3];   // (512,)
    const float* vvec = (const float*)d_in[4];   // (512,)
    float* out = (float*)d_out;                  // (32, 4096)

    unsigned short* wsB = (unsigned short*)d_ws;               // 512 KB bf16 W_e
    float* wsP1 = (float*)((char*)d_ws + 524288);              // 64 KB proj1
    float* wsS1 = (float*)((char*)d_ws + 589824);              // 512 KB partial

    hipLaunchKernelGGL(prep_kernel, dim3(96), dim3(512), 0, stream,
                       dh, Wat, batt, wsB, wsP1);
    hipLaunchKernelGGL(fused_kernel, dim3(4096), dim3(256), 0, stream,
                       enc, wsB, wsP1, vvec, out, wsS1);
    hipLaunchKernelGGL(softmax_kernel, dim3(32), dim3(256), 0, stream, out, wsS1);
}

// Round 7
// 167.103 us; speedup vs baseline: 1.3211x; 1.3211x over previous
//
#include <hip/hip_runtime.h>
#include <hip/hip_bf16.h>
#include <stdint.h>

// B=32, S=4096, ENC=512, DEC=512
// out = softmax_s( sum_d tanh( enc @ W_e^T + dh @ W_h^T + b ) * v )

typedef __attribute__((ext_vector_type(8))) short short8;
typedef __attribute__((ext_vector_type(4))) float f32x4;

static __device__ __forceinline__ short8 cvt8(float4 a, float4 b) {
    // 4x v_cvt_pk_bf16_f32 (RNE)
    union { short8 s; __hip_bfloat162 h[4]; } u;
    u.h[0] = __float22bfloat162_rn(float2{a.x, a.y});
    u.h[1] = __float22bfloat162_rn(float2{a.z, a.w});
    u.h[2] = __float22bfloat162_rn(float2{b.x, b.y});
    u.h[3] = __float22bfloat162_rn(float2{b.z, b.w});
    return u.s;
}

static __device__ __forceinline__ float tanh_fast(float x) {
    // tanh(x) = 1 - 2/(exp(2x)+1); overflow->+1, underflow->-1 (both correct)
    return 1.0f - 2.0f / (__expf(2.0f * x) + 1.0f);
}

// ---------------------------------------------------------------------------
// Kernel 1 (96 blocks x 512):
//   blocks 0..63 : W_e (= W_attn[:,512:]) -> bf16, LINEAR [n(512)][k(512)]
//                  (1 KB rows) -- read as MFMA B-fragments by kernel 2.
//   blocks 64..95: proj1[b][e] = sum_d dh[b,d]*W_attn[e,d] + b_attn[e]
// ---------------------------------------------------------------------------
__global__ __launch_bounds__(512) void prep_kernel(
    const float* __restrict__ dh, const float* __restrict__ W_attn,
    const float* __restrict__ b_attn, unsigned short* __restrict__ wsB,
    float* __restrict__ wsP1) {
    __shared__ float dhs[512];
    const int tid = threadIdx.x;
    if (blockIdx.x < 64) {
        int idx = blockIdx.x * 512 + tid;       // 0..32767
        int n  = idx >> 6;                      // W_e row (output dim d)
        int c8 = idx & 63;                      // 8-elem chunk in row
        const float* src = W_attn + (size_t)n * 1024 + 512 + c8 * 8;
        float4 f0 = *(const float4*)(src);
        float4 f1 = *(const float4*)(src + 4);
        *(short8*)((char*)wsB + (size_t)n * 1024 + c8 * 16) = cvt8(f0, f1);
    } else {
        int b = blockIdx.x - 64;
        dhs[tid] = dh[b * 512 + tid];
        __syncthreads();
        const float* wrow = W_attn + (size_t)tid * 1024;  // W_h row e=tid
        float acc = 0.f;
        #pragma unroll 8
        for (int d = 0; d < 512; d += 4) {
            float4 w = *(const float4*)(wrow + d);
            acc += dhs[d] * w.x + dhs[d + 1] * w.y + dhs[d + 2] * w.z + dhs[d + 3] * w.w;
        }
        wsP1[b * 512 + tid] = acc + b_attn[tid];
    }
}

// ---------------------------------------------------------------------------
// Kernel 2: persistent fused GEMM. 256 blocks (1/CU), 512 thr = 8 waves.
// Block owns 1024 enc rows x 256 cols (cb half of N=512); loops 16 M-tiles
// of 64 rows. Wave owns 32 cols; its FULL B panel (32 x 512 bf16) lives in
// 128 VGPRs, loaded once from wsB. A tile (64x512 f32 -> bf16) staged whole
// into a 64KB LDS dbuf while computing the previous tile: 128 continuous
// kt-steps per block, 2 barriers per tile, nothing in vmem flight at them.
// Partner blocks (cb=0/1, same rows) sit 8 apart in blockIdx -> same XCD ->
// enc fetched once from HBM, shared via L2.
// ---------------------------------------------------------------------------
__global__ __launch_bounds__(512, 2) void fused_kernel(
    const float* __restrict__ enc, const unsigned short* __restrict__ wsB,
    const float* __restrict__ wsP1, const float* __restrict__ vvec,
    float* __restrict__ out, float* __restrict__ wsS1) {
    __shared__ char lds[133120];                 // 2 x 64KB A dbuf + 2KB red
    float* const red = (float*)(lds + 131072);   // [8 waves][64 rows]

    const int tid  = threadIdx.x;
    const int wave = tid >> 6;
    const int lane = tid & 63;
    const int llo  = lane & 15, lhi = lane >> 4;

    // block -> (cb, mslot): partners (cb=0,1 of same mslot) differ by 8 in
    // blockIdx -> same XCD under round-robin dispatch.
    const int bid   = blockIdx.x;            // 0..255
    const int xr    = bid & 7, j = bid >> 3; // j 0..31
    const int cb    = j & 1;
    const int mslot = xr * 16 + (j >> 1);    // 0..127
    const int m0b   = mslot * 1024;
    const int b     = m0b >> 12;             // batch; 1024-row slice in one b

    // ---- B panel -> registers (once) ----
    short8 breg[8][2][2];                    // [kt][kk][ni] = 128 VGPR
    {
        const char* bbase = (const char*)wsB +
            (size_t)(cb * 256 + wave * 32 + llo) * 1024 + lhi * 16;
        #pragma unroll
        for (int kt = 0; kt < 8; ++kt)
            #pragma unroll
            for (int kk = 0; kk < 2; ++kk)
                #pragma unroll
                for (int ni = 0; ni < 2; ++ni)
                    breg[kt][kk][ni] = *(const short8*)(bbase +
                        (size_t)ni * 16 * 1024 + kt * 128 + kk * 64);
    }
    float p1v[2], vv[2];
    #pragma unroll
    for (int ni = 0; ni < 2; ++ni) {
        int d = cb * 256 + wave * 32 + ni * 16 + llo;
        p1v[ni] = wsP1[b * 512 + d];
        vv[ni]  = vvec[d];
    }

    // A staging map: thread -> (row srow, kt-chunk skc); one thread stages one
    // row's 64-f32 K-chunk (= one kt) as swizzled ds_write_b128s.
    const int srow = tid >> 3, skc = tid & 7;
    const int swz  = (srow & 7) << 4;

    #define A_ISSUE(t1, p, L)                                                  \
        do { const float* as_ = enc + (size_t)(m0b + (t1) * 64 + srow) * 512 + \
                                skc * 64 + (p) * 32;                           \
             _Pragma("unroll")                                                 \
             for (int q_ = 0; q_ < 8; ++q_)                                    \
                 L[q_] = *(const float4*)(as_ + q_ * 4); } while (0)

    #define A_WRITE(Adst, p, L)                                               \
        do { _Pragma("unroll")                                                 \
             for (int c_ = 0; c_ < 4; ++c_) {                                  \
                 int c8_ = (p) * 4 + c_;                                       \
                 *(short8*)((Adst) + skc * 8192 + srow * 128 +                 \
                            ((c8_ * 16) ^ swz)) = cvt8(L[c_ * 2], L[c_ * 2 + 1]); \
             } } while (0)

    #define COMPUTE(Asrc, kt)                                                  \
        do { _Pragma("unroll")                                                 \
             for (int kk = 0; kk < 2; ++kk) {                                  \
                 short8 af[4];                                                 \
                 _Pragma("unroll")                                             \
                 for (int mi = 0; mi < 4; ++mi) {                              \
                     int row = mi * 16 + llo;                                  \
                     af[mi] = *(const short8*)((Asrc) + (kt) * 8192 +          \
                         row * 128 + ((kk * 64 + lhi * 16) ^ ((row & 7) << 4))); \
                 }                                                             \
                 _Pragma("unroll")                                             \
                 for (int mi = 0; mi < 4; ++mi)                                \
                     _Pragma("unroll")                                         \
                     for (int ni = 0; ni < 2; ++ni)                            \
                         acc[mi][ni] = __builtin_amdgcn_mfma_f32_16x16x32_bf16(\
                             af[mi], breg[kt][kk][ni], acc[mi][ni], 0, 0, 0);  \
             } } while (0)

    f32x4 acc[4][2];
    float4 L[8];

    // prologue: stage tile 0 into buffer 0
    A_ISSUE(0, 0, L); A_WRITE(lds, 0, L);
    A_ISSUE(0, 1, L); A_WRITE(lds, 1, L);
    __syncthreads();

    for (int t = 0; t < 16; ++t) {
        char* const Acur = lds + ((t & 1) ? 65536 : 0);
        char* const Anxt = lds + ((t & 1) ? 0 : 65536);
        const bool more = (t < 15);

        #pragma unroll
        for (int mi = 0; mi < 4; ++mi)
            #pragma unroll
            for (int ni = 0; ni < 2; ++ni)
                acc[mi][ni] = f32x4{0.f, 0.f, 0.f, 0.f};

        if (more) A_ISSUE(t + 1, 0, L);      // HBM loads fly under kt 0..3
        COMPUTE(Acur, 0); COMPUTE(Acur, 1);
        COMPUTE(Acur, 2); COMPUTE(Acur, 3);
        if (more) { A_WRITE(Anxt, 0, L); A_ISSUE(t + 1, 1, L); }
        COMPUTE(Acur, 4); COMPUTE(Acur, 5);
        COMPUTE(Acur, 6); COMPUTE(Acur, 7);
        if (more) A_WRITE(Anxt, 1, L);

        // --- per-tile epilogue: tanh(acc + proj1)*v, reduce over d ---
        float part[16];
        #pragma unroll
        for (int mi = 0; mi < 4; ++mi)
            #pragma unroll
            for (int r = 0; r < 4; ++r) {
                float s = tanh_fast(acc[mi][0][r] + p1v[0]) * vv[0]
                        + tanh_fast(acc[mi][1][r] + p1v[1]) * vv[1];
                part[mi * 4 + r] = s;
            }
        #pragma unroll
        for (int off = 1; off < 16; off <<= 1)
            #pragma unroll
            for (int i = 0; i < 16; ++i)
                part[i] += __shfl_xor(part[i], off, 64);
        if (llo == 0) {
            #pragma unroll
            for (int mi = 0; mi < 4; ++mi)
                #pragma unroll
                for (int r = 0; r < 4; ++r)
                    red[wave * 64 + mi * 16 + lhi * 4 + r] = part[mi * 4 + r];
        }
        __syncthreads();   // red ready + Anxt published (no vmem in flight)
        if (tid < 64) {
            float s = 0.f;
            #pragma unroll
            for (int w = 0; w < 8; ++w) s += red[w * 64 + tid];
            (cb ? wsS1 : out)[m0b + t * 64 + tid] = s;
        }
        __syncthreads();   // red reusable next tile
    }
}

// ---------------------------------------------------------------------------
// Kernel 3: add the two column-half partials, row softmax over S=4096,
// write to out. 32 blocks x 256.
// ---------------------------------------------------------------------------
__global__ __launch_bounds__(256) void softmax_kernel(
    float* __restrict__ out, const float* __restrict__ wsS1) {
    __shared__ float wred[8];
    const int b = blockIdx.x, tid = threadIdx.x;
    float* row = out + (size_t)b * 4096;
    const float* row1 = wsS1 + (size_t)b * 4096;
    float vals[16];
    float lmax = -1e30f;
    #pragma unroll
    for (int i = 0; i < 16; ++i) {
        vals[i] = row[i * 256 + tid] + row1[i * 256 + tid];
        lmax = fmaxf(lmax, vals[i]);
    }
    #pragma unroll
    for (int off = 32; off >= 1; off >>= 1)
        lmax = fmaxf(lmax, __shfl_xor(lmax, off, 64));
    if ((tid & 63) == 0) wred[tid >> 6] = lmax;
    __syncthreads();
    float gmax = fmaxf(fmaxf(wred[0], wred[1]), fmaxf(wred[2], wred[3]));
    float lsum = 0.f;
    #pragma unroll
    for (int i = 0; i < 16; ++i) {
        vals[i] = expf(vals[i] - gmax);
        lsum += vals[i];
    }
    #pragma unroll
    for (int off = 32; off >= 1; off >>= 1)
        lsum += __shfl_xor(lsum, off, 64);
    if ((tid & 63) == 0) wred[4 + (tid >> 6)] = lsum;
    __syncthreads();
    float inv = 1.f / (wred[4] + wred[5] + wred[6] + wred[7]);
    #pragma unroll
    for (int i = 0; i < 16; ++i)
        row[i * 256 + tid] = vals[i] * inv;
}

extern "C" void kernel_launch(void* const* d_in, const int* in_sizes, int n_in,
                              void* d_out, int out_size, void* d_ws, size_t ws_size,
                              hipStream_t stream) {
    const float* dh   = (const float*)d_in[0];   // (32, 512)
    const float* enc  = (const float*)d_in[1];   // (32, 4096, 512)
    const float* Wat  = (const float*)d_in[2];   // (512, 1024)
    const float* batt = (const float*)d_in[3];   // (512,)
    const float* vvec = (const float*)d_in[4];   // (512,)
    float* out = (float*)d_out;                  // (32, 4096)

    unsigned short* wsB = (unsigned short*)d_ws;               // 512 KB bf16 W_e
    float* wsP1 = (float*)((char*)d_ws + 524288);              // 64 KB proj1
    float* wsS1 = (float*)((char*)d_ws + 589824);              // 512 KB partial

    hipLaunchKernelGGL(prep_kernel, dim3(96), dim3(512), 0, stream,
                       dh, Wat, batt, wsB, wsP1);
    hipLaunchKernelGGL(fused_kernel, dim3(256), dim3(512), 0, stream,
                       enc, wsB, wsP1, vvec, out, wsS1);
    hipLaunchKernelGGL(softmax_kernel, dim3(32), dim3(256), 0, stream, out, wsS1);
}

// Round 8
// 146.921 us; speedup vs baseline: 1.5025x; 1.1374x over previous
//
#include <hip/hip_runtime.h>
#include <hip/hip_bf16.h>
#include <stdint.h>

// B=32, S=4096, ENC=512, DEC=512
// out = softmax_s( sum_d tanh( enc @ W_e^T + dh @ W_h^T + b ) * v )

typedef __attribute__((ext_vector_type(8))) short short8;
typedef __attribute__((ext_vector_type(4))) float f32x4;

static __device__ __forceinline__ short8 cvt8(float4 a, float4 b) {
    // 4x v_cvt_pk_bf16_f32 (RNE)
    union { short8 s; __hip_bfloat162 h[4]; } u;
    u.h[0] = __float22bfloat162_rn(float2{a.x, a.y});
    u.h[1] = __float22bfloat162_rn(float2{a.z, a.w});
    u.h[2] = __float22bfloat162_rn(float2{b.x, b.y});
    u.h[3] = __float22bfloat162_rn(float2{b.z, b.w});
    return u.s;
}

static __device__ __forceinline__ float tanh_fast(float x) {
    // tanh(x) = 1 - 2/(exp(2x)+1); overflow->+1, underflow->-1 (both correct)
    return 1.0f - 2.0f / (__expf(2.0f * x) + 1.0f);
}

// ---------------------------------------------------------------------------
// Kernel 1 (96 blocks x 512):
//   blocks 0..63 : W_e (= W_attn[:,512:]) -> bf16, K-tiled [kt][n(512)][64],
//                  128B rows, 16B-group XOR swizzle (^ (n&7)<<4) so the main
//                  kernel stages linearly via global_load_lds.
//   blocks 64..95: proj1[b][e] = sum_d dh[b,d]*W_attn[e,d] + b_attn[e]
// ---------------------------------------------------------------------------
__global__ __launch_bounds__(512) void prep_kernel(
    const float* __restrict__ dh, const float* __restrict__ W_attn,
    const float* __restrict__ b_attn, unsigned short* __restrict__ wsB,
    float* __restrict__ wsP1) {
    __shared__ float dhs[512];
    const int tid = threadIdx.x;
    if (blockIdx.x < 64) {
        int idx = blockIdx.x * 512 + tid;      // 0..32767
        int c8 = idx & 7;                       // 16B group in row
        int n  = (idx >> 3) & 511;              // W_e row (output dim d)
        int kt = idx >> 12;                     // K tile 0..7
        const float* src = W_attn + (size_t)n * 1024 + 512 + kt * 64 + c8 * 8;
        float4 f0 = *(const float4*)(src);
        float4 f1 = *(const float4*)(src + 4);
        int row = kt * 512 + n;
        int byteInRow = (c8 * 16) ^ ((n & 7) << 4);
        *(short8*)((char*)wsB + (size_t)row * 128 + byteInRow) = cvt8(f0, f1);
    } else {
        int b = blockIdx.x - 64;
        dhs[tid] = dh[b * 512 + tid];
        __syncthreads();
        const float* wrow = W_attn + (size_t)tid * 1024;  // W_h row e=tid
        float acc = 0.f;
        #pragma unroll 8
        for (int d = 0; d < 512; d += 4) {
            float4 w = *(const float4*)(wrow + d);
            acc += dhs[d] * w.x + dhs[d + 1] * w.y + dhs[d + 2] * w.z + dhs[d + 3] * w.w;
        }
        wsP1[b * 512 + tid] = acc + b_attn[tid];
    }
}

// ---------------------------------------------------------------------------
// Kernel 2: fused GEMM (64 rows x 256 cols per block, K=512) + tanh + v-dot.
// 256 thr = 4 waves, 1M x 4N; wave tile 64x64 = 4x4 frags of 16x16x32 bf16.
// R3 geometry (best measured) with three changes:
//   1. ROLLED K-loop (#pragma unroll 1) -- one ~3KB body, no I-cache thrash.
//   2. A double-buffered (2x8KB) -- A-write decoupled from the barrier pair.
//   3. Counted vmcnt(4) at the B-publish barrier -- next A-tile's 4 HBM
//      loads stay in flight across BOTH barriers (never drained mid-loop).
// LDS 48KB (A 2x8 + B 32) -> 3 blocks/CU.
// cb=0 writes partial scores to out, cb=1 to wsS1; softmax adds them.
// ---------------------------------------------------------------------------
__global__ __launch_bounds__(256, 3) void fused_kernel(
    const float* __restrict__ enc, const unsigned short* __restrict__ wsB,
    const float* __restrict__ wsP1, const float* __restrict__ vvec,
    float* __restrict__ out, float* __restrict__ wsS1) {
    __shared__ char lds[49152];
    // A buffers: lds + p*8192, [64][128B] bf16 swizzled
    char* const B_lds = lds + 16384;    // [256][128B] bf16 swizzled

    const int tid  = threadIdx.x;
    const int wc   = tid >> 6;                    // wave = N-block 0..3
    const int lane = tid & 63;
    const int llo  = lane & 15, lhi = lane >> 4;

    // XCD-chunked swizzle; (rb, cb=0/1) pairs adjacent logical blocks ->
    // same XCD -> shared enc tile L2-hot.
    const int bid = blockIdx.x;
    const int lb  = (bid & 7) * 512 + (bid >> 3);
    const int rb  = lb >> 1, cb = lb & 1;
    const int m0  = rb * 64;
    const int b   = m0 >> 12;                     // batch (64 | 4096)

    // A staging map: thread -> (row ar, 16-f32 K chunk ac)
    const int ar = tid >> 2, ac = tid & 3;
    const float* aptr = enc + (size_t)(m0 + ar) * 512 + ac * 16;
    const int aoff0 = ar * 128 + (((ac * 32)     ) ^ ((ar & 7) << 4));
    const int aoff1 = ar * 128 + (((ac * 32) + 16) ^ ((ar & 7) << 4));
    const char* bbase = (const char*)wsB + cb * 32768;

    f32x4 acc[4][4] = {};
    float4 fa0, fa1, fa2, fa3;

    #define SCHEDB() __builtin_amdgcn_sched_barrier(0)
    #define BAR() __builtin_amdgcn_s_barrier()

    #define A_LOAD(kt)                                 \
        do { const float* p_ = aptr + (kt) * 64;       \
             fa0 = *(const float4*)(p_);               \
             fa1 = *(const float4*)(p_ + 4);           \
             fa2 = *(const float4*)(p_ + 8);           \
             fa3 = *(const float4*)(p_ + 12); } while (0)

    #define A_WRITE(Adst)                              \
        do { *(short8*)((Adst) + aoff0) = cvt8(fa0, fa1); \
             *(short8*)((Adst) + aoff1) = cvt8(fa2, fa3); } while (0)

    #define B_GLDS(kt)                                                             \
        do { const char* bsrc_ = bbase + (size_t)(kt) * 65536;                     \
             _Pragma("unroll")                                                     \
             for (int i_ = 0; i_ < 8; ++i_) {                                      \
                 int off_ = i_ * 4096 + wc * 1024;                                 \
                 __builtin_amdgcn_global_load_lds(                                 \
                     (const uint32_t __attribute__((address_space(1)))*)(bsrc_ + off_ + lane * 16), \
                     (uint32_t __attribute__((address_space(3)))*)(B_lds + off_),  \
                     16, 0, 0);                                                    \
             } } while (0)

    #define COMPUTE(Asrc)                                                          \
        do { _Pragma("unroll")                                                     \
             for (int kk = 0; kk < 2; ++kk) {                                      \
                 const int gbyte = kk * 64 + lhi * 16;                             \
                 short8 af[4], bfr[4];                                             \
                 _Pragma("unroll")                                                 \
                 for (int mi = 0; mi < 4; ++mi) {                                  \
                     int row = mi * 16 + llo;                                      \
                     af[mi] = *(const short8*)((Asrc) + row * 128 +                \
                                               (gbyte ^ ((row & 7) << 4)));        \
                 }                                                                 \
                 _Pragma("unroll")                                                 \
                 for (int ni = 0; ni < 4; ++ni) {                                  \
                     int n = wc * 64 + ni * 16 + llo;                              \
                     bfr[ni] = *(const short8*)(B_lds + n * 128 +                  \
                                                (gbyte ^ ((n & 7) << 4)));         \
                 }                                                                 \
                 _Pragma("unroll")                                                 \
                 for (int mi = 0; mi < 4; ++mi)                                    \
                     _Pragma("unroll")                                             \
                     for (int ni = 0; ni < 4; ++ni)                                \
                         acc[mi][ni] = __builtin_amdgcn_mfma_f32_16x16x32_bf16(    \
                             af[mi], bfr[ni], acc[mi][ni], 0, 0, 0);               \
             } } while (0)

    // ---- prologue: stage A(0)+B(0); leave A(1) in flight ----
    A_LOAD(0);
    A_WRITE(lds);                 // compiler waits A(0) regs
    B_GLDS(0);                    // vm +8
    A_LOAD(1);                    // vm +4 -> 12
    asm volatile("s_waitcnt vmcnt(4) lgkmcnt(0)" ::: "memory"); // B(0) in LDS, writes drained
    SCHEDB(); BAR(); SCHEDB();

    // ---- rolled main loop: one barrier pair per kt, A never drained ----
    #pragma unroll 1
    for (int kt = 0; kt < 7; ++kt) {
        COMPUTE(lds + (kt & 1) * 8192);
        A_WRITE(lds + ((kt + 1) & 1) * 8192);   // other A-buf; compiler waits A(kt+1) regs
        asm volatile("s_waitcnt lgkmcnt(0)" ::: "memory");  // my reads+writes drained
        SCHEDB(); BAR(); SCHEDB();              // all waves done with B(kt), A staged
        B_GLDS(kt + 1);                         // vm +8 (overwrites B, now safe)
        if (kt < 6) {
            A_LOAD(kt + 2);                     // vm +4 -> stays in flight
            asm volatile("s_waitcnt vmcnt(4)" ::: "memory");   // B(kt+1) done, A flies
        } else {
            asm volatile("s_waitcnt vmcnt(0)" ::: "memory");   // tail: drain B(7)
        }
        SCHEDB(); BAR(); SCHEDB();              // B(kt+1) published everywhere
    }
    COMPUTE(lds + 8192);           // kt = 7 (odd buffer)
    __syncthreads();               // seal K-loop before LDS reuse

    // --- epilogue: tanh(acc + proj1[b,d]) * v[d], partial-reduce over d ---
    float p1v[4], vv[4];
    #pragma unroll
    for (int ni = 0; ni < 4; ++ni) {
        int d = cb * 256 + wc * 64 + ni * 16 + llo;
        p1v[ni] = wsP1[b * 512 + d];
        vv[ni]  = vvec[d];
    }
    float part[16];
    #pragma unroll
    for (int mi = 0; mi < 4; ++mi)
        #pragma unroll
        for (int r = 0; r < 4; ++r) {
            float s = 0.f;
            #pragma unroll
            for (int ni = 0; ni < 4; ++ni)
                s += tanh_fast(acc[mi][ni][r] + p1v[ni]) * vv[ni];
            part[mi * 4 + r] = s;
        }
    // reduce across the 16-lane column group (lane bits 0..3)
    #pragma unroll
    for (int off = 1; off < 16; off <<= 1)
        #pragma unroll
        for (int i = 0; i < 16; ++i)
            part[i] += __shfl_xor(part[i], off, 64);

    float* red = (float*)lds;   // [4 wc][64 rows]; K-loop done, safe to reuse
    if (llo == 0) {
        #pragma unroll
        for (int mi = 0; mi < 4; ++mi)
            #pragma unroll
            for (int r = 0; r < 4; ++r)
                red[wc * 64 + mi * 16 + lhi * 4 + r] = part[mi * 4 + r];
    }
    __syncthreads();
    if (tid < 64) {
        float s = red[tid] + red[64 + tid] + red[128 + tid] + red[192 + tid];
        (cb ? wsS1 : out)[m0 + tid] = s;
    }
}

// ---------------------------------------------------------------------------
// Kernel 3: add the two column-half partials, row softmax over S=4096,
// write to out. 32 blocks x 256.
// ---------------------------------------------------------------------------
__global__ __launch_bounds__(256) void softmax_kernel(
    float* __restrict__ out, const float* __restrict__ wsS1) {
    __shared__ float wred[8];
    const int b = blockIdx.x, tid = threadIdx.x;
    float* row = out + (size_t)b * 4096;
    const float* row1 = wsS1 + (size_t)b * 4096;
    float vals[16];
    float lmax = -1e30f;
    #pragma unroll
    for (int i = 0; i < 16; ++i) {
        vals[i] = row[i * 256 + tid] + row1[i * 256 + tid];
        lmax = fmaxf(lmax, vals[i]);
    }
    #pragma unroll
    for (int off = 32; off >= 1; off >>= 1)
        lmax = fmaxf(lmax, __shfl_xor(lmax, off, 64));
    if ((tid & 63) == 0) wred[tid >> 6] = lmax;
    __syncthreads();
    float gmax = fmaxf(fmaxf(wred[0], wred[1]), fmaxf(wred[2], wred[3]));
    float lsum = 0.f;
    #pragma unroll
    for (int i = 0; i < 16; ++i) {
        vals[i] = expf(vals[i] - gmax);
        lsum += vals[i];
    }
    #pragma unroll
    for (int off = 32; off >= 1; off >>= 1)
        lsum += __shfl_xor(lsum, off, 64);
    if ((tid & 63) == 0) wred[4 + (tid >> 6)] = lsum;
    __syncthreads();
    float inv = 1.f / (wred[4] + wred[5] + wred[6] + wred[7]);
    #pragma unroll
    for (int i = 0; i < 16; ++i)
        row[i * 256 + tid] = vals[i] * inv;
}

extern "C" void kernel_launch(void* const* d_in, const int* in_sizes, int n_in,
                              void* d_out, int out_size, void* d_ws, size_t ws_size,
                              hipStream_t stream) {
    const float* dh   = (const float*)d_in[0];   // (32, 512)
    const float* enc  = (const float*)d_in[1];   // (32, 4096, 512)
    const float* Wat  = (const float*)d_in[2];   // (512, 1024)
    const float* batt = (const float*)d_in[3];   // (512,)
    const float* vvec = (const float*)d_in[4];   // (512,)
    float* out = (float*)d_out;                  // (32, 4096)

    unsigned short* wsB = (unsigned short*)d_ws;               // 512 KB bf16 W_e
    float* wsP1 = (float*)((char*)d_ws + 524288);              // 64 KB proj1
    float* wsS1 = (float*)((char*)d_ws + 589824);              // 512 KB partial

    hipLaunchKernelGGL(prep_kernel, dim3(96), dim3(512), 0, stream,
                       dh, Wat, batt, wsB, wsP1);
    hipLaunchKernelGGL(fused_kernel, dim3(4096), dim3(256), 0, stream,
                       enc, wsB, wsP1, vvec, out, wsS1);
    hipLaunchKernelGGL(softmax_kernel, dim3(32), dim3(256), 0, stream, out, wsS1);
}

// Round 9
// 144.075 us; speedup vs baseline: 1.5322x; 1.0198x over previous
//
#include <hip/hip_runtime.h>
#include <hip/hip_bf16.h>
#include <stdint.h>

// B=32, S=4096, ENC=512, DEC=512
// out = softmax_s( sum_d tanh( enc @ W_e^T + dh @ W_h^T + b ) * v )

typedef __attribute__((ext_vector_type(8))) short short8;
typedef __attribute__((ext_vector_type(4))) float f32x4;

static __device__ __forceinline__ short8 cvt8(float4 a, float4 b) {
    // 4x v_cvt_pk_bf16_f32 (RNE)
    union { short8 s; __hip_bfloat162 h[4]; } u;
    u.h[0] = __float22bfloat162_rn(float2{a.x, a.y});
    u.h[1] = __float22bfloat162_rn(float2{a.z, a.w});
    u.h[2] = __float22bfloat162_rn(float2{b.x, b.y});
    u.h[3] = __float22bfloat162_rn(float2{b.z, b.w});
    return u.s;
}

static __device__ __forceinline__ float tanh_fast(float x) {
    // tanh(x) = 1 - 2/(exp(2x)+1); overflow->+1, underflow->-1 (both correct)
    return 1.0f - 2.0f / (__expf(2.0f * x) + 1.0f);
}

// ---------------------------------------------------------------------------
// Kernel 1 (96 blocks x 512):
//   blocks 0..63 : W_e (= W_attn[:,512:]) -> bf16, K-tiled by 32:
//                  [kt(16)][n(512)][64B row], 16B-slot XOR swizzle
//                  (slot ^= (n>>1)&3) -- 2-way-only bank aliasing on read.
//   blocks 64..95: proj1[b][e] = sum_d dh[b,d]*W_attn[e,d] + b_attn[e]
// ---------------------------------------------------------------------------
__global__ __launch_bounds__(512) void prep_kernel(
    const float* __restrict__ dh, const float* __restrict__ W_attn,
    const float* __restrict__ b_attn, unsigned short* __restrict__ wsB,
    float* __restrict__ wsP1) {
    __shared__ float dhs[512];
    const int tid = threadIdx.x;
    if (blockIdx.x < 64) {
        int idx = blockIdx.x * 512 + tid;       // 0..32767
        int n  = idx >> 6;                      // W_e row (output dim d)
        int c  = idx & 63;                      // 8-elem k-chunk 0..63
        int kt = c >> 2, c8 = c & 3;            // K-tile, 16B slot in 64B row
        const float* src = W_attn + (size_t)n * 1024 + 512 + c * 8;
        float4 f0 = *(const float4*)(src);
        float4 f1 = *(const float4*)(src + 4);
        int dst = (kt * 512 + n) * 64 + ((c8 * 16) ^ (((n >> 1) & 3) << 4));
        *(short8*)((char*)wsB + dst) = cvt8(f0, f1);
    } else {
        int b = blockIdx.x - 64;
        dhs[tid] = dh[b * 512 + tid];
        __syncthreads();
        const float* wrow = W_attn + (size_t)tid * 1024;  // W_h row e=tid
        float acc = 0.f;
        #pragma unroll 8
        for (int d = 0; d < 512; d += 4) {
            float4 w = *(const float4*)(wrow + d);
            acc += dhs[d] * w.x + dhs[d + 1] * w.y + dhs[d + 2] * w.z + dhs[d + 3] * w.w;
        }
        wsP1[b * 512 + tid] = acc + b_attn[tid];
    }
}

// ---------------------------------------------------------------------------
// Kernel 2: fused GEMM (64 rows x 256 cols per block, K=512) + tanh + v-dot.
// 256 thr = 4 waves 1Mx4N; wave tile 64x64 = 4x4 frags of 16x16x32 bf16.
// BK=32, BOTH A and B double-buffered, ONE barrier per iter, counted vmcnt:
//   iter: B_glds(kt+1->nxt); COMPUTE(cur); A_write(nxt); A_load(kt+2);
//         s_waitcnt vmcnt(2) lgkm(0); s_barrier.
// B's L2 latency hides under COMPUTE; A's HBM latency spans a full iter;
// vmcnt never drains to 0 mid-loop. LDS = 40960 (A 2x4K + B 2x16K) and
// ~128 total regs -> 4 blocks/CU (the R3-measured best-occupancy point).
// cb=0 writes partial scores to out, cb=1 to wsS1; softmax adds them.
// ---------------------------------------------------------------------------
__global__ __launch_bounds__(256, 4) void fused_kernel(
    const float* __restrict__ enc, const unsigned short* __restrict__ wsB,
    const float* __restrict__ wsP1, const float* __restrict__ vvec,
    float* __restrict__ out, float* __restrict__ wsS1) {
    __shared__ char lds[40960];
    // A0 [0,4K) A1 [4K,8K) : [64][64B] swz.  B0 [8K,24K) B1 [24K,40K) : [256][64B] swz.

    const int tid  = threadIdx.x;
    const int wc   = tid >> 6;                    // wave = N-block 0..3
    const int lane = tid & 63;
    const int llo  = lane & 15, lhi = lane >> 4;

    // XCD-chunked swizzle; (rb, cb=0/1) pairs adjacent logical blocks ->
    // same XCD -> shared enc tile fetched from HBM once (L2-hot for partner).
    const int bid = blockIdx.x;
    const int lb  = (bid & 7) * 512 + (bid >> 3);
    const int rb  = lb >> 1, cb = lb & 1;
    const int m0  = rb * 64;
    const int b   = m0 >> 12;                     // batch (64 | 4096)

    // A staging: thread -> (row ar, 16B slot aslot); 8 f32 -> 1 ds_write_b128
    const int ar = tid >> 2, aslot = tid & 3;
    const float* aptr = enc + (size_t)(m0 + ar) * 512 + aslot * 8;
    const int aoff = ar * 64 + ((aslot * 16) ^ (((ar >> 1) & 3) << 4));
    const char* bbase = (const char*)wsB + cb * 16384;

    f32x4 acc[4][4] = {};
    float4 fa0, fa1;

    #define SCHEDB() __builtin_amdgcn_sched_barrier(0)
    #define BAR() __builtin_amdgcn_s_barrier()

    #define A_LOAD(kt)                                 \
        do { const float* p_ = aptr + (kt) * 32;       \
             fa0 = *(const float4*)(p_);               \
             fa1 = *(const float4*)(p_ + 4); } while (0)

    #define A_WRITE(Adst)                              \
        do { *(short8*)((Adst) + aoff) = cvt8(fa0, fa1); } while (0)

    #define B_GLDS(kt, Bdst)                                                       \
        do { const char* bsrc_ = bbase + (size_t)(kt) * 32768;                     \
             _Pragma("unroll")                                                     \
             for (int i_ = 0; i_ < 4; ++i_) {                                      \
                 int off_ = wc * 4096 + i_ * 1024;                                 \
                 __builtin_amdgcn_global_load_lds(                                 \
                     (const uint32_t __attribute__((address_space(1)))*)(bsrc_ + off_ + lane * 16), \
                     (uint32_t __attribute__((address_space(3)))*)((Bdst) + off_), \
                     16, 0, 0);                                                    \
             } } while (0)

    #define COMPUTE(Asrc, Bsrc)                                                    \
        do { short8 af[4], bfr[4];                                                 \
             _Pragma("unroll")                                                     \
             for (int mi = 0; mi < 4; ++mi) {                                      \
                 int row = mi * 16 + llo;                                          \
                 af[mi] = *(const short8*)((Asrc) + row * 64 +                     \
                           ((lhi * 16) ^ (((row >> 1) & 3) << 4)));                \
             }                                                                     \
             _Pragma("unroll")                                                     \
             for (int ni = 0; ni < 4; ++ni) {                                      \
                 int n = wc * 64 + ni * 16 + llo;                                  \
                 bfr[ni] = *(const short8*)((Bsrc) + n * 64 +                      \
                           ((lhi * 16) ^ (((n >> 1) & 3) << 4)));                  \
             }                                                                     \
             __builtin_amdgcn_s_setprio(1);                                        \
             _Pragma("unroll")                                                     \
             for (int mi = 0; mi < 4; ++mi)                                        \
                 _Pragma("unroll")                                                 \
                 for (int ni = 0; ni < 4; ++ni)                                    \
                     acc[mi][ni] = __builtin_amdgcn_mfma_f32_16x16x32_bf16(        \
                         af[mi], bfr[ni], acc[mi][ni], 0, 0, 0);                   \
             __builtin_amdgcn_s_setprio(0); } while (0)

    // ---- prologue: stage tile 0, leave A(1) in flight ----
    A_LOAD(0);                                   // vm: A0[2]
    B_GLDS(0, lds + 8192);                       // vm: +B0[4] = 6
    A_WRITE(lds);                                // auto-wait vmcnt(4): A0 landed
    A_LOAD(1);                                   // vm: B0[4] + A1[2]
    asm volatile("s_waitcnt vmcnt(2) lgkmcnt(0)" ::: "memory"); // B0 + A-write done
    SCHEDB(); BAR(); SCHEDB();

    // ---- main loop: ONE barrier per iter, vmcnt >= 2 always ----
    #pragma unroll 1
    for (int kt = 0; kt < 14; ++kt) {
        char* const Acur = lds + (kt & 1) * 4096;
        char* const Anxt = lds + ((kt & 1) ^ 1) * 4096;
        char* const Bcur = lds + 8192 + (kt & 1) * 16384;
        char* const Bnxt = lds + 8192 + ((kt & 1) ^ 1) * 16384;
        B_GLDS(kt + 1, Bnxt);      // vm: A(kt+1)[2] + B(kt+1)[4]
        SCHEDB();                  // pin issue before compute
        COMPUTE(Acur, Bcur);       // B latency hides here
        A_WRITE(Anxt);             // auto-wait vmcnt(4): A(kt+1) regs landed
        A_LOAD(kt + 2);            // vm: +2, flies across barrier
        asm volatile("s_waitcnt vmcnt(2) lgkmcnt(0)" ::: "memory"); // B(kt+1) done
        SCHEDB(); BAR(); SCHEDB();
    }
    // kt = 14 (cur = buf0): last stage, drain fully
    B_GLDS(15, lds + 8192 + 16384);
    SCHEDB();
    COMPUTE(lds, lds + 8192);
    A_WRITE(lds + 4096);           // auto-wait A(15)
    asm volatile("s_waitcnt vmcnt(0) lgkmcnt(0)" ::: "memory");
    SCHEDB(); BAR(); SCHEDB();
    // kt = 15
    COMPUTE(lds + 4096, lds + 8192 + 16384);
    __syncthreads();               // seal K-loop before LDS reuse

    // --- epilogue: tanh(acc + proj1[b,d]) * v[d], partial-reduce over d ---
    float p1v[4], vv[4];
    #pragma unroll
    for (int ni = 0; ni < 4; ++ni) {
        int d = cb * 256 + wc * 64 + ni * 16 + llo;
        p1v[ni] = wsP1[b * 512 + d];
        vv[ni]  = vvec[d];
    }
    float part[16];
    #pragma unroll
    for (int mi = 0; mi < 4; ++mi)
        #pragma unroll
        for (int r = 0; r < 4; ++r) {
            float s = 0.f;
            #pragma unroll
            for (int ni = 0; ni < 4; ++ni)
                s += tanh_fast(acc[mi][ni][r] + p1v[ni]) * vv[ni];
            part[mi * 4 + r] = s;
        }
    // reduce across the 16-lane column group (lane bits 0..3)
    #pragma unroll
    for (int off = 1; off < 16; off <<= 1)
        #pragma unroll
        for (int i = 0; i < 16; ++i)
            part[i] += __shfl_xor(part[i], off, 64);

    float* red = (float*)lds;   // [4 wc][64 rows]; K-loop done, safe to reuse
    if (llo == 0) {
        #pragma unroll
        for (int mi = 0; mi < 4; ++mi)
            #pragma unroll
            for (int r = 0; r < 4; ++r)
                red[wc * 64 + mi * 16 + lhi * 4 + r] = part[mi * 4 + r];
    }
    __syncthreads();
    if (tid < 64) {
        float s = red[tid] + red[64 + tid] + red[128 + tid] + red[192 + tid];
        (cb ? wsS1 : out)[m0 + tid] = s;
    }
}

// ---------------------------------------------------------------------------
// Kernel 3: add the two column-half partials, row softmax over S=4096,
// write to out. 32 blocks x 256.
// ---------------------------------------------------------------------------
__global__ __launch_bounds__(256) void softmax_kernel(
    float* __restrict__ out, const float* __restrict__ wsS1) {
    __shared__ float wred[8];
    const int b = blockIdx.x, tid = threadIdx.x;
    float* row = out + (size_t)b * 4096;
    const float* row1 = wsS1 + (size_t)b * 4096;
    float vals[16];
    float lmax = -1e30f;
    #pragma unroll
    for (int i = 0; i < 16; ++i) {
        vals[i] = row[i * 256 + tid] + row1[i * 256 + tid];
        lmax = fmaxf(lmax, vals[i]);
    }
    #pragma unroll
    for (int off = 32; off >= 1; off >>= 1)
        lmax = fmaxf(lmax, __shfl_xor(lmax, off, 64));
    if ((tid & 63) == 0) wred[tid >> 6] = lmax;
    __syncthreads();
    float gmax = fmaxf(fmaxf(wred[0], wred[1]), fmaxf(wred[2], wred[3]));
    float lsum = 0.f;
    #pragma unroll
    for (int i = 0; i < 16; ++i) {
        vals[i] = expf(vals[i] - gmax);
        lsum += vals[i];
    }
    #pragma unroll
    for (int off = 32; off >= 1; off >>= 1)
        lsum += __shfl_xor(lsum, off, 64);
    if ((tid & 63) == 0) wred[4 + (tid >> 6)] = lsum;
    __syncthreads();
    float inv = 1.f / (wred[4] + wred[5] + wred[6] + wred[7]);
    #pragma unroll
    for (int i = 0; i < 16; ++i)
        row[i * 256 + tid] = vals[i] * inv;
}

extern "C" void kernel_launch(void* const* d_in, const int* in_sizes, int n_in,
                              void* d_out, int out_size, void* d_ws, size_t ws_size,
                              hipStream_t stream) {
    const float* dh   = (const float*)d_in[0];   // (32, 512)
    const float* enc  = (const float*)d_in[1];   // (32, 4096, 512)
    const float* Wat  = (const float*)d_in[2];   // (512, 1024)
    const float* batt = (const float*)d_in[3];   // (512,)
    const float* vvec = (const float*)d_in[4];   // (512,)
    float* out = (float*)d_out;                  // (32, 4096)

    unsigned short* wsB = (unsigned short*)d_ws;               // 512 KB bf16 W_e
    float* wsP1 = (float*)((char*)d_ws + 524288);              // 64 KB proj1
    float* wsS1 = (float*)((char*)d_ws + 589824);              // 512 KB partial

    hipLaunchKernelGGL(prep_kernel, dim3(96), dim3(512), 0, stream,
                       dh, Wat, batt, wsB, wsP1);
    hipLaunchKernelGGL(fused_kernel, dim3(4096), dim3(256), 0, stream,
                       enc, wsB, wsP1, vvec, out, wsS1);
    hipLaunchKernelGGL(softmax_kernel, dim3(32), dim3(256), 0, stream, out, wsS1);
}